// Round 1
// baseline (14513.881 us; speedup 1.0000x reference)
//
#include <hip/hip_runtime.h>
#include <math.h>

#define B_    32
#define T_    128
#define IN_   256
#define H_    512
#define N_    128
#define R_    4
#define W_    64
#define RW_   256
#define FOUT_ 256
#define IF_   471
#define EPSF  1e-6f

// ---------- workspace layout (float offsets) ----------
#define OFF_H0   0          // H*B   (transposed [k][b])
#define OFF_H1   16384
#define OFF_C    32768      // H*B   ([j][b])
#define OFF_LR   49152      // RW*B  ([k][b])
#define OFF_XI   57344      // IF*B  ([row][b])
#define OFF_MEM  72416      // B*N*W
#define OFF_LINK 334560     // B*N*N
#define OFF_PREC 858848     // B*N
#define OFF_RW   862944     // B*R*N
#define OFF_WW   879328     // B*N
#define OFF_USG  883424     // B*N
#define WS_TOTAL 887520

__device__ __forceinline__ float sig_(float x)   { return 1.0f / (1.0f + expf(-x)); }
__device__ __forceinline__ float splus_(float x) { return fmaxf(x, 0.0f) + log1pf(expf(-fabsf(x))); }

__global__ void k_init(float* p, int n) {
    for (int i = blockIdx.x * blockDim.x + threadIdx.x; i < n; i += gridDim.x * blockDim.x)
        p[i] = 0.0f;
}

// Phase 1: gates GEMV + LSTM update for step t, plus out(t-1) rows.
// grid: 96 blocks x 256 thr = 32 batches x 768 rows (512 gate-j + 256 out rows)
__global__ void k_gates(const float* __restrict__ x, const float* __restrict__ Wih,
                        const float* __restrict__ Whh, const float* __restrict__ bih,
                        const float* __restrict__ bhh, const float* __restrict__ Wemb,
                        const float* __restrict__ bemb,
                        const float* __restrict__ hprev, float* __restrict__ hnew,
                        float* __restrict__ c, const float* __restrict__ lr,
                        float* __restrict__ out, int t)
{
    int tid = blockIdx.x * blockDim.x + threadIdx.x;
    int b = tid & 31;
    int row = tid >> 5;
    if (row < H_) {
        int j = row;
        float a0 = bih[j]        + bhh[j];
        float a1 = bih[H_ + j]   + bhh[H_ + j];
        float a2 = bih[2*H_ + j] + bhh[2*H_ + j];
        float a3 = bih[3*H_ + j] + bhh[3*H_ + j];
        const float* wi0 = Wih + (size_t)(0*H_ + j) * 512;
        const float* wi1 = Wih + (size_t)(1*H_ + j) * 512;
        const float* wi2 = Wih + (size_t)(2*H_ + j) * 512;
        const float* wi3 = Wih + (size_t)(3*H_ + j) * 512;
        const float* xb = x + ((size_t)b * T_ + t) * IN_;
        for (int k = 0; k < IN_; ++k) {
            float v = xb[k];
            a0 += wi0[k]*v; a1 += wi1[k]*v; a2 += wi2[k]*v; a3 += wi3[k]*v;
        }
        for (int k = 0; k < RW_; ++k) {
            float v = lr[k*B_ + b];
            a0 += wi0[IN_+k]*v; a1 += wi1[IN_+k]*v; a2 += wi2[IN_+k]*v; a3 += wi3[IN_+k]*v;
        }
        const float* wh0 = Whh + (size_t)(0*H_ + j) * H_;
        const float* wh1 = Whh + (size_t)(1*H_ + j) * H_;
        const float* wh2 = Whh + (size_t)(2*H_ + j) * H_;
        const float* wh3 = Whh + (size_t)(3*H_ + j) * H_;
        for (int k = 0; k < H_; ++k) {
            float v = hprev[k*B_ + b];
            a0 += wh0[k]*v; a1 += wh1[k]*v; a2 += wh2[k]*v; a3 += wh3[k]*v;
        }
        float ig = sig_(a0), fg = sig_(a1), gg = tanhf(a2), og = sig_(a3);
        float cn = fg * c[j*B_ + b] + ig * gg;
        c[j*B_ + b] = cn;
        hnew[j*B_ + b] = og * tanhf(cn);
    } else if (t > 0) {
        int r = row - H_;  // 0..255
        float acc = bemb[r];
        const float* we = Wemb + (size_t)r * (H_ + RW_);
        for (int k = 0; k < H_; ++k)  acc += we[k]      * hprev[k*B_ + b];
        for (int k = 0; k < RW_; ++k) acc += we[H_ + k] * lr[k*B_ + b];
        out[((size_t)b * T_ + (t-1)) * FOUT_ + r] = acc;
    }
}

// Final-step output (t = T-1)
__global__ void k_out(const float* __restrict__ Wemb, const float* __restrict__ bemb,
                      const float* __restrict__ h, const float* __restrict__ lr,
                      float* __restrict__ out)
{
    int tid = blockIdx.x * blockDim.x + threadIdx.x;
    int b = tid & 31;
    int r = tid >> 5;
    if (r >= FOUT_) return;
    float acc = bemb[r];
    const float* we = Wemb + (size_t)r * (H_ + RW_);
    for (int k = 0; k < H_; ++k)  acc += we[k]      * h[k*B_ + b];
    for (int k = 0; k < RW_; ++k) acc += we[H_ + k] * lr[k*B_ + b];
    out[((size_t)b * T_ + (T_-1)) * FOUT_ + r] = acc;
}

// Phase 2: xi = h @ W_if.T + b_if (raw, nonlinearities applied in k_mem)
__global__ void k_xi(const float* __restrict__ Wif, const float* __restrict__ bif,
                     const float* __restrict__ h, float* __restrict__ xi)
{
    int tid = blockIdx.x * blockDim.x + threadIdx.x;
    int b = tid & 31;
    int row = tid >> 5;
    if (row >= IF_) return;
    float acc = bif[row];
    const float* w = Wif + (size_t)row * H_;
    for (int k = 0; k < H_; ++k) acc += w[k] * h[k*B_ + b];
    xi[row*B_ + b] = acc;
}

// Phase 3: memory machine, one block per batch.
__global__ __launch_bounds__(256) void k_mem(const float* __restrict__ xi,
        float* __restrict__ mem, float* __restrict__ link, float* __restrict__ prec,
        float* __restrict__ rw, float* __restrict__ ww, float* __restrict__ usg,
        float* __restrict__ lr)
{
    int b = blockIdx.x;
    int tid = threadIdx.x;

    __shared__ float s_mem[N_ * (W_ + 1)];
    __shared__ float s_rw[R_*N_], s_rwn[R_*N_], s_fwd[R_*N_], s_bwd[R_*N_], s_cr[R_*N_];
    __shared__ float s_bpart[4][R_][N_];
    __shared__ float s_cw[N_], s_usage[N_], s_alloc[N_], s_ww[N_], s_wwp[N_], s_prec[N_], s_minv[N_];
    __shared__ float s_rkeys[R_*W_], s_wkey[W_], s_ev[W_], s_wv[W_];
    __shared__ float s_rstr[R_], s_fg[R_], s_modes[R_*3], s_kinv[R_];
    __shared__ float s_sc[8]; // 0=wstr 1=alloc_g 2=write_g 3=max 4=invsum 5=wkey_inv 6=sum_ww
    __shared__ unsigned long long s_key[N_];

    // 1. load & parse interface vector
    for (int i = tid; i < IF_; i += 256) {
        float v = xi[i*B_ + b];
        if      (i < 256) s_rkeys[i]       = tanhf(v);
        else if (i < 260) s_rstr[i-256]    = splus_(v);
        else if (i < 324) s_wkey[i-260]    = tanhf(v);
        else if (i < 325) s_sc[0]          = splus_(v);
        else if (i < 389) s_ev[i-325]      = sig_(v);
        else if (i < 453) s_wv[i-389]      = tanhf(v);
        else if (i < 457) s_fg[i-453]      = sig_(v);
        else if (i < 458) s_sc[1]          = sig_(v);
        else if (i < 459) s_sc[2]          = sig_(v);
        else              s_modes[i-459]   = v;
    }
    // 2. load state
    for (int i = tid; i < R_*N_; i += 256) s_rw[i] = rw[(size_t)b*R_*N_ + i];
    if (tid < N_) {
        s_usage[tid] = usg[b*N_ + tid];
        s_wwp[tid]   = ww[b*N_ + tid];
        s_prec[tid]  = prec[b*N_ + tid];
    }
    for (int i = tid; i < N_*W_; i += 256)
        s_mem[(i >> 6) * (W_+1) + (i & 63)] = mem[(size_t)b*N_*W_ + i];
    __syncthreads();

    // read_modes softmax (per head)
    if (tid < R_) {
        float m0 = s_modes[tid*3], m1 = s_modes[tid*3+1], m2 = s_modes[tid*3+2];
        float mx = fmaxf(m0, fmaxf(m1, m2));
        float e0 = expf(m0-mx), e1 = expf(m1-mx), e2 = expf(m2-mx);
        float inv = 1.0f / (e0 + e1 + e2);
        s_modes[tid*3] = e0*inv; s_modes[tid*3+1] = e1*inv; s_modes[tid*3+2] = e2*inv;
    }
    // 3. retention psi, usage update, sort keys, pre-update mem norms
    if (tid < N_) {
        float p = 1.0f;
        #pragma unroll
        for (int r = 0; r < R_; ++r) p *= 1.0f - s_fg[r] * s_rw[r*N_ + tid];
        float u = s_usage[tid], w0 = s_wwp[tid];
        u = (u + w0 - u*w0) * p;
        s_usage[tid] = u;
        usg[b*N_ + tid] = u;
        unsigned int fb = __float_as_uint(u);
        fb = (fb & 0x80000000u) ? ~fb : (fb | 0x80000000u);
        s_key[tid] = ((unsigned long long)fb << 32) | (unsigned int)tid;
        float s = 0.0f;
        for (int w = 0; w < W_; ++w) { float m = s_mem[tid*(W_+1)+w]; s += m*m; }
        s_minv[tid] = 1.0f / (sqrtf(s) + EPSF);
    }
    if (tid == 0) {
        float s = 0.0f;
        for (int w = 0; w < W_; ++w) s += s_wkey[w]*s_wkey[w];
        s_sc[5] = 1.0f / (sqrtf(s) + EPSF);
    }
    __syncthreads();

    // 4. bitonic sort (stable ascending via index in low bits)
    for (int k = 2; k <= N_; k <<= 1) {
        for (int j = k >> 1; j > 0; j >>= 1) {
            if (tid < N_) {
                int l = tid ^ j;
                if (l > tid) {
                    unsigned long long a = s_key[tid], bb = s_key[l];
                    bool asc = ((tid & k) == 0);
                    if ((a > bb) == asc) { s_key[tid] = bb; s_key[l] = a; }
                }
            }
            __syncthreads();
        }
    }
    // 5. cumprod + allocation scatter
    if (tid == 0) {
        float cp = 1.0f;
        for (int i = 0; i < N_; ++i) {
            int idx = (int)(s_key[i] & 0xffffffffu);
            float su = s_usage[idx];
            s_alloc[idx] = (1.0f - su) * cp;
            cp *= su;
        }
    }
    __syncthreads();
    // 6. write-content addressing (pre-update mem)
    if (tid < N_) {
        float d = 0.0f;
        for (int w = 0; w < W_; ++w) d += s_wkey[w] * s_mem[tid*(W_+1)+w];
        s_cw[tid] = d * s_minv[tid] * s_sc[5] * s_sc[0];
    }
    __syncthreads();
    if (tid == 0) {
        float mx = -1e30f;
        for (int i = 0; i < N_; ++i) mx = fmaxf(mx, s_cw[i]);
        s_sc[3] = mx;
    }
    __syncthreads();
    if (tid < N_) s_cw[tid] = expf(s_cw[tid] - s_sc[3]);
    __syncthreads();
    if (tid == 0) {
        float s = 0.0f;
        for (int i = 0; i < N_; ++i) s += s_cw[i];
        s_sc[4] = 1.0f / s;
    }
    __syncthreads();
    // 7. write weighting
    if (tid < N_) {
        float cwn = s_cw[tid] * s_sc[4];
        float w = s_sc[2] * (s_sc[1] * s_alloc[tid] + (1.0f - s_sc[1]) * cwn);
        s_ww[tid] = w;
        ww[b*N_ + tid] = w;
    }
    __syncthreads();
    // 8. memory update
    for (int i = tid; i < N_*W_; i += 256) {
        int n = i >> 6, w = i & 63;
        float m = s_mem[n*(W_+1)+w];
        m = m * (1.0f - s_ww[n]*s_ev[w]) + s_ww[n]*s_wv[w];
        s_mem[n*(W_+1)+w] = m;
        mem[(size_t)b*N_*W_ + i] = m;
    }
    __syncthreads();
    // 9. fused link update + fwd reduce + bwd partials (single pass over link)
    {
        int wv = tid >> 6, lane = tid & 63;
        float bl0[R_], bl1[R_];
        #pragma unroll
        for (int r = 0; r < R_; ++r) { bl0[r] = 0.0f; bl1[r] = 0.0f; }
        size_t base = (size_t)b * N_ * N_;
        for (int row = wv*32; row < wv*32 + 32; ++row) {
            float wwr = s_ww[row];
            float l0 = link[base + row*N_ + lane];
            float l1 = link[base + row*N_ + 64 + lane];
            float n0 = (1.0f - wwr - s_ww[lane])      * l0 + wwr * s_prec[lane];
            float n1 = (1.0f - wwr - s_ww[64 + lane]) * l1 + wwr * s_prec[64 + lane];
            if (row == lane)      n0 = 0.0f;
            if (row == 64 + lane) n1 = 0.0f;
            link[base + row*N_ + lane]      = n0;
            link[base + row*N_ + 64 + lane] = n1;
            #pragma unroll
            for (int r = 0; r < R_; ++r) {
                float v = n0 * s_rw[r*N_ + lane] + n1 * s_rw[r*N_ + 64 + lane];
                v += __shfl_xor(v, 32); v += __shfl_xor(v, 16); v += __shfl_xor(v, 8);
                v += __shfl_xor(v, 4);  v += __shfl_xor(v, 2);  v += __shfl_xor(v, 1);
                if (lane == 0) s_fwd[r*N_ + row] = v;
                bl0[r] += n0 * s_rw[r*N_ + row];
                bl1[r] += n1 * s_rw[r*N_ + row];
            }
        }
        #pragma unroll
        for (int r = 0; r < R_; ++r) {
            s_bpart[wv][r][lane]      = bl0[r];
            s_bpart[wv][r][64 + lane] = bl1[r];
        }
    }
    __syncthreads();
    if (tid < N_) {
        #pragma unroll
        for (int r = 0; r < R_; ++r)
            s_bwd[r*N_ + tid] = s_bpart[0][r][tid] + s_bpart[1][r][tid]
                              + s_bpart[2][r][tid] + s_bpart[3][r][tid];
    }
    if (tid == 0) {
        float s = 0.0f;
        for (int i = 0; i < N_; ++i) s += s_ww[i];
        s_sc[6] = s;
    }
    __syncthreads();
    // precedence update + post-update mem norms
    if (tid < N_) {
        float p = (1.0f - s_sc[6]) * s_prec[tid] + s_ww[tid];
        s_prec[tid] = p;
        prec[b*N_ + tid] = p;
        float s = 0.0f;
        for (int w = 0; w < W_; ++w) { float m = s_mem[tid*(W_+1)+w]; s += m*m; }
        s_minv[tid] = 1.0f / (sqrtf(s) + EPSF);
    }
    if (tid >= 128 && tid < 128 + R_) {
        int r = tid - 128;
        float s = 0.0f;
        for (int w = 0; w < W_; ++w) { float kv = s_rkeys[r*W_+w]; s += kv*kv; }
        s_kinv[r] = 1.0f / (sqrtf(s) + EPSF);
    }
    __syncthreads();
    // 10. read-content addressing (post-update mem)
    for (int i = tid; i < R_*N_; i += 256) {
        int r = i >> 7, n = i & 127;
        float d = 0.0f;
        for (int w = 0; w < W_; ++w) d += s_rkeys[r*W_+w] * s_mem[n*(W_+1)+w];
        s_cr[i] = d * s_minv[n] * s_kinv[r] * s_rstr[r];
    }
    __syncthreads();
    if (tid < R_) {
        int r = tid;
        float mx = -1e30f;
        for (int n = 0; n < N_; ++n) mx = fmaxf(mx, s_cr[r*N_+n]);
        float s = 0.0f;
        for (int n = 0; n < N_; ++n) { float e = expf(s_cr[r*N_+n] - mx); s_cr[r*N_+n] = e; s += e; }
        float inv = 1.0f / s;
        for (int n = 0; n < N_; ++n) s_cr[r*N_+n] *= inv;
    }
    __syncthreads();
    // 11. new read weights
    for (int i = tid; i < R_*N_; i += 256) {
        int r = i >> 7;
        float v = s_modes[r*3] * s_bwd[i] + s_modes[r*3+1] * s_cr[i] + s_modes[r*3+2] * s_fwd[i];
        s_rwn[i] = v;
        rw[(size_t)b*R_*N_ + i] = v;
    }
    __syncthreads();
    // 12. read vectors -> last_read (transposed [k][b])
    for (int i = tid; i < R_*W_; i += 256) {
        int r = i >> 6, w = i & 63;
        float d = 0.0f;
        for (int n = 0; n < N_; ++n) d += s_rwn[r*N_ + n] * s_mem[n*(W_+1)+w];
        lr[i*B_ + b] = d;
    }
}

extern "C" void kernel_launch(void* const* d_in, const int* in_sizes, int n_in,
                              void* d_out, int out_size, void* d_ws, size_t ws_size,
                              hipStream_t stream)
{
    const float* x    = (const float*)d_in[0];
    const float* Wih  = (const float*)d_in[1];
    const float* Whh  = (const float*)d_in[2];
    const float* bih  = (const float*)d_in[3];
    const float* bhh  = (const float*)d_in[4];
    const float* Wif  = (const float*)d_in[5];
    const float* bif  = (const float*)d_in[6];
    const float* Wemb = (const float*)d_in[7];
    const float* bemb = (const float*)d_in[8];
    float* out = (float*)d_out;
    float* ws  = (float*)d_ws;

    float* h0   = ws + OFF_H0;
    float* h1   = ws + OFF_H1;
    float* c    = ws + OFF_C;
    float* lr   = ws + OFF_LR;
    float* xi   = ws + OFF_XI;
    float* mem  = ws + OFF_MEM;
    float* link = ws + OFF_LINK;
    float* prec = ws + OFF_PREC;
    float* rwp  = ws + OFF_RW;
    float* wwp  = ws + OFF_WW;
    float* usg  = ws + OFF_USG;

    k_init<<<512, 256, 0, stream>>>(ws, WS_TOTAL);

    for (int t = 0; t < T_; ++t) {
        const float* hp = (t & 1) ? h1 : h0;
        float*       hn = (t & 1) ? h0 : h1;
        k_gates<<<96, 256, 0, stream>>>(x, Wih, Whh, bih, bhh, Wemb, bemb,
                                        hp, hn, c, lr, out, t);
        k_xi<<<59, 256, 0, stream>>>(Wif, bif, hn, xi);
        k_mem<<<32, 256, 0, stream>>>(xi, mem, link, prec, rwp, wwp, usg, lr);
    }
    // final h is in buffer (T&1)==0 -> h0
    k_out<<<32, 256, 0, stream>>>(Wemb, bemb, h0, lr, out);
}

// Round 2
// 8653.371 us; speedup vs baseline: 1.6773x; 1.6773x over previous
//
#include <hip/hip_runtime.h>
#include <math.h>

#define B_    32
#define T_    128
#define IN_   256
#define H_    512
#define N_    128
#define R_    4
#define W_    64
#define RW_   256
#define FOUT_ 256
#define IF_   471
#define EPSF  1e-6f
#define KT_   256
#define KPAD  260

// ---------- workspace layout (float offsets) ----------
#define OFF_H0   0
#define OFF_H1   (H_*B_)                 // 16384
#define OFF_C    (2*H_*B_)               // 32768
#define OFF_LR   (3*H_*B_)               // 49152
#define OFF_XI   (OFF_LR + RW_*B_)       // 57344 (480 rows padded)
#define OFF_MEM  (OFF_XI + 480*B_)       // 72704
#define OFF_LINK (OFF_MEM + B_*N_*W_)    // 334848
#define OFF_PREC (OFF_LINK + B_*N_*N_)   // 859136
#define OFF_RW   (OFF_PREC + B_*N_)      // 863232
#define OFF_WW   (OFF_RW + B_*R_*N_)     // 879616
#define OFF_USG  (OFF_WW + B_*N_)        // 883712
#define WS_STATE (OFF_USG + B_*N_)       // 887808 floats

__device__ __forceinline__ float sig_(float x)   { return 1.0f / (1.0f + expf(-x)); }
__device__ __forceinline__ float splus_(float x) { return fmaxf(x, 0.0f) + log1pf(expf(-fabsf(x))); }

__device__ __forceinline__ unsigned long long shflx64(unsigned long long v, int m) {
    unsigned int lo = (unsigned int)v, hi = (unsigned int)(v >> 32);
    lo = (unsigned int)__shfl_xor((int)lo, m);
    hi = (unsigned int)__shfl_xor((int)hi, m);
    return ((unsigned long long)hi << 32) | lo;
}

__global__ void k_init(float* p, int n) {
    for (int i = blockIdx.x * blockDim.x + threadIdx.x; i < n; i += gridDim.x * blockDim.x)
        p[i] = 0.0f;
}

// ---- stage a [256][32] tile from [k][b]-major source into lds[b][k] ----
__device__ __forceinline__ void stage_kb(const float* __restrict__ src, float* lds, int tid) {
    #pragma unroll
    for (int i = 0; i < 8; ++i) {
        int f = i * 256 + tid;            // float4 index in [0,2048)
        int k = f >> 3;
        int b4 = (f & 7) << 2;
        float4 v = reinterpret_cast<const float4*>(src)[f];
        lds[(b4 + 0) * KPAD + k] = v.x;
        lds[(b4 + 1) * KPAD + k] = v.y;
        lds[(b4 + 2) * KPAD + k] = v.z;
        lds[(b4 + 3) * KPAD + k] = v.w;
    }
}

// ---- stage x_t (b-major source) with transpose into lds[b][k] ----
__device__ __forceinline__ void stage_x(const float* __restrict__ x, int t, float* lds, int tid) {
    #pragma unroll
    for (int i = 0; i < 8; ++i) {
        int f = i * 256 + tid;            // [0,2048)
        int b  = f >> 6;
        int k4 = (f & 63) << 2;
        float4 v = *reinterpret_cast<const float4*>(x + ((size_t)b * T_ + t) * IN_ + k4);
        *reinterpret_cast<float4*>(&lds[b * KPAD + k4]) = v;   // b*1040B -> 16B aligned
    }
}

// ---- 4-row MAC over one staged tile ----
__device__ __forceinline__ void tile_mac4(const float* lds,
        const float* __restrict__ w0p, const float* __restrict__ w1p,
        const float* __restrict__ w2p, const float* __restrict__ w3p,
        int lane, float* v)
{
    float4 w0 = *reinterpret_cast<const float4*>(w0p + lane * 4);
    float4 w1 = *reinterpret_cast<const float4*>(w1p + lane * 4);
    float4 w2 = *reinterpret_cast<const float4*>(w2p + lane * 4);
    float4 w3 = *reinterpret_cast<const float4*>(w3p + lane * 4);
    #pragma unroll
    for (int b = 0; b < 32; ++b) {
        float4 a = *reinterpret_cast<const float4*>(lds + b * KPAD + lane * 4);
        v[0*32+b] = fmaf(w0.w, a.w, fmaf(w0.z, a.z, fmaf(w0.y, a.y, fmaf(w0.x, a.x, v[0*32+b]))));
        v[1*32+b] = fmaf(w1.w, a.w, fmaf(w1.z, a.z, fmaf(w1.y, a.y, fmaf(w1.x, a.x, v[1*32+b]))));
        v[2*32+b] = fmaf(w2.w, a.w, fmaf(w2.z, a.z, fmaf(w2.y, a.y, fmaf(w2.x, a.x, v[2*32+b]))));
        v[3*32+b] = fmaf(w3.w, a.w, fmaf(w3.z, a.z, fmaf(w3.y, a.y, fmaf(w3.x, a.x, v[3*32+b]))));
    }
}

// ---- butterfly fold: 128 per-lane partials -> 2 fully-reduced values/lane ----
// final: lane holds idx = s + 2*(lane&15)*... : r=(lane>>4)&3, b=2*(lane&15)+s
__device__ __forceinline__ void fold128(float* v, int lane) {
    #define FOLD_STAGE(D, HALF) { _Pragma("unroll") \
        for (int i = 0; i < HALF; ++i) { \
            float a_ = v[i], c_ = v[i + HALF]; \
            float t_ = (lane & D) ? a_ : c_; \
            t_ = __shfl_xor(t_, D); \
            v[i] = (lane & D) ? (c_ + t_) : (a_ + t_); } }
    FOLD_STAGE(32, 64) FOLD_STAGE(16, 32) FOLD_STAGE(8, 16)
    FOLD_STAGE(4, 8)   FOLD_STAGE(2, 4)   FOLD_STAGE(1, 2)
    #undef FOLD_STAGE
}

// Phase 1: blocks 0..127: LSTM gates (wave = one unit j, 4 gate rows).
//          blocks 128..143: out(t-1) rows (wave = 4 rows of Wemb).
__global__ __launch_bounds__(256) void k_gates(
        const float* __restrict__ x, const float* __restrict__ Wih,
        const float* __restrict__ Whh, const float* __restrict__ bih,
        const float* __restrict__ bhh, const float* __restrict__ Wemb,
        const float* __restrict__ bemb,
        const float* __restrict__ hprev, float* __restrict__ hnew,
        float* __restrict__ c, const float* __restrict__ lr,
        float* __restrict__ out, int t)
{
    __shared__ float lds[32 * KPAD];
    __shared__ float sg[4][4][32];
    int tid = threadIdx.x, lane = tid & 63, wid = tid >> 6;
    float v[128];
    #pragma unroll
    for (int i = 0; i < 128; ++i) v[i] = 0.0f;

    if (blockIdx.x < 128) {
        int j = blockIdx.x * 4 + wid;
        for (int kt = 0; kt < 4; ++kt) {
            __syncthreads();
            if (kt == 0)      stage_x(x, t, lds, tid);
            else if (kt == 1) stage_kb(lr, lds, tid);
            else              stage_kb(hprev + (kt - 2) * KT_ * B_, lds, tid);
            __syncthreads();
            const float *w0, *w1, *w2, *w3;
            if (kt < 2) {
                w0 = Wih + ((size_t)(0*H_ + j)) * 512 + kt * 256;
                w1 = Wih + ((size_t)(1*H_ + j)) * 512 + kt * 256;
                w2 = Wih + ((size_t)(2*H_ + j)) * 512 + kt * 256;
                w3 = Wih + ((size_t)(3*H_ + j)) * 512 + kt * 256;
            } else {
                w0 = Whh + ((size_t)(0*H_ + j)) * 512 + (kt - 2) * 256;
                w1 = Whh + ((size_t)(1*H_ + j)) * 512 + (kt - 2) * 256;
                w2 = Whh + ((size_t)(2*H_ + j)) * 512 + (kt - 2) * 256;
                w3 = Whh + ((size_t)(3*H_ + j)) * 512 + (kt - 2) * 256;
            }
            tile_mac4(lds, w0, w1, w2, w3, lane, v);
        }
        fold128(v, lane);
        int r = (lane >> 4) & 3, b0 = (lane & 15) * 2;
        sg[wid][r][b0]     = v[0];
        sg[wid][r][b0 + 1] = v[1];
        __syncthreads();
        if (lane < 32) {
            int b = lane;
            float ai = sg[wid][0][b] + bih[j]          + bhh[j];
            float af = sg[wid][1][b] + bih[H_ + j]     + bhh[H_ + j];
            float ag = sg[wid][2][b] + bih[2*H_ + j]   + bhh[2*H_ + j];
            float ao = sg[wid][3][b] + bih[3*H_ + j]   + bhh[3*H_ + j];
            float ig = sig_(ai), fg = sig_(af), gg = tanhf(ag), og = sig_(ao);
            float cn = fg * c[j*B_ + b] + ig * gg;
            c[j*B_ + b] = cn;
            hnew[j*B_ + b] = og * tanhf(cn);
        }
    } else {
        if (t == 0) return;
        int rowbase = (blockIdx.x - 128) * 16 + wid * 4;
        for (int kt = 0; kt < 3; ++kt) {
            __syncthreads();
            if (kt < 2) stage_kb(hprev + kt * KT_ * B_, lds, tid);
            else        stage_kb(lr, lds, tid);
            __syncthreads();
            const float* w0 = Wemb + (size_t)(rowbase + 0) * 768 + kt * 256;
            const float* w1 = Wemb + (size_t)(rowbase + 1) * 768 + kt * 256;
            const float* w2 = Wemb + (size_t)(rowbase + 2) * 768 + kt * 256;
            const float* w3 = Wemb + (size_t)(rowbase + 3) * 768 + kt * 256;
            tile_mac4(lds, w0, w1, w2, w3, lane, v);
        }
        fold128(v, lane);
        int rloc = (lane >> 4) & 3, b0 = (lane & 15) * 2;
        int row = rowbase + rloc;
        float bb = bemb[row];
        out[((size_t)b0       * T_ + (t-1)) * FOUT_ + row] = v[0] + bb;
        out[((size_t)(b0 + 1) * T_ + (t-1)) * FOUT_ + row] = v[1] + bb;
    }
}

// Final-step output rows (uses final h, lr)
__global__ __launch_bounds__(256) void k_out(
        const float* __restrict__ Wemb, const float* __restrict__ bemb,
        const float* __restrict__ h, const float* __restrict__ lr,
        float* __restrict__ out)
{
    __shared__ float lds[32 * KPAD];
    int tid = threadIdx.x, lane = tid & 63, wid = tid >> 6;
    float v[128];
    #pragma unroll
    for (int i = 0; i < 128; ++i) v[i] = 0.0f;
    int rowbase = blockIdx.x * 16 + wid * 4;
    for (int kt = 0; kt < 3; ++kt) {
        __syncthreads();
        if (kt < 2) stage_kb(h + kt * KT_ * B_, lds, tid);
        else        stage_kb(lr, lds, tid);
        __syncthreads();
        const float* w0 = Wemb + (size_t)(rowbase + 0) * 768 + kt * 256;
        const float* w1 = Wemb + (size_t)(rowbase + 1) * 768 + kt * 256;
        const float* w2 = Wemb + (size_t)(rowbase + 2) * 768 + kt * 256;
        const float* w3 = Wemb + (size_t)(rowbase + 3) * 768 + kt * 256;
        tile_mac4(lds, w0, w1, w2, w3, lane, v);
    }
    fold128(v, lane);
    int rloc = (lane >> 4) & 3, b0 = (lane & 15) * 2;
    int row = rowbase + rloc;
    float bb = bemb[row];
    out[((size_t)b0       * T_ + (T_-1)) * FOUT_ + row] = v[0] + bb;
    out[((size_t)(b0 + 1) * T_ + (T_-1)) * FOUT_ + row] = v[1] + bb;
}

// Phase 2: xi = h @ W_if.T + b_if (raw)
__global__ __launch_bounds__(256) void k_xi(
        const float* __restrict__ Wif, const float* __restrict__ bif,
        const float* __restrict__ h, float* __restrict__ xi)
{
    __shared__ float lds[32 * KPAD];
    int tid = threadIdx.x, lane = tid & 63, wid = tid >> 6;
    float v[128];
    #pragma unroll
    for (int i = 0; i < 128; ++i) v[i] = 0.0f;
    int rowbase = blockIdx.x * 16 + wid * 4;
    int r0 = min(rowbase + 0, IF_ - 1), r1 = min(rowbase + 1, IF_ - 1);
    int r2 = min(rowbase + 2, IF_ - 1), r3 = min(rowbase + 3, IF_ - 1);
    for (int kt = 0; kt < 2; ++kt) {
        __syncthreads();
        stage_kb(h + kt * KT_ * B_, lds, tid);
        __syncthreads();
        tile_mac4(lds, Wif + (size_t)r0 * 512 + kt * 256, Wif + (size_t)r1 * 512 + kt * 256,
                       Wif + (size_t)r2 * 512 + kt * 256, Wif + (size_t)r3 * 512 + kt * 256,
                  lane, v);
    }
    fold128(v, lane);
    int rloc = (lane >> 4) & 3, b0 = (lane & 15) * 2;
    int row = rowbase + rloc;
    if (row < IF_) {
        float bb = bif[row];
        xi[row * B_ + b0]     = v[0] + bb;
        xi[row * B_ + b0 + 1] = v[1] + bb;
    }
}

// Phase 3: memory machine, one block per batch.
__global__ __launch_bounds__(256) void k_mem(const float* __restrict__ xi,
        float* __restrict__ mem, float* __restrict__ link, float* __restrict__ prec,
        float* __restrict__ rw, float* __restrict__ ww, float* __restrict__ usg,
        float* __restrict__ lr)
{
    const int b = blockIdx.x, tid = threadIdx.x;
    const int lane = tid & 63, wid = tid >> 6;

    __shared__ float s_mem[N_ * (W_ + 1)];
    __shared__ float s_rw[R_*N_], s_fwd[R_*N_], s_bwd[R_*N_], s_cr[R_*N_];
    __shared__ float s_bpart[4][R_][N_];
    __shared__ float s_cw[N_], s_usage[N_], s_alloc[N_], s_ww[N_], s_prec[N_], s_minv[N_];
    __shared__ float s_rkeys[R_*W_], s_wkey[W_], s_ev[W_], s_wv[W_];
    __shared__ float s_rstr[R_], s_fg[R_], s_modes[R_*3], s_kinv[R_], s_m1[R_];
    __shared__ float s_sc[8]; // 0=wstr 1=alloc_g 2=write_g 4=cw_invsum 5=wkey_inv 6=sum_ww 7=scan_tot0
    __shared__ unsigned long long s_key[N_];

    // 1. parse interface + load state
    for (int i = tid; i < IF_; i += 256) {
        float vv = xi[i*B_ + b];
        if      (i < 256) s_rkeys[i]     = tanhf(vv);
        else if (i < 260) s_rstr[i-256]  = splus_(vv);
        else if (i < 324) s_wkey[i-260]  = tanhf(vv);
        else if (i < 325) s_sc[0]        = splus_(vv);
        else if (i < 389) s_ev[i-325]    = sig_(vv);
        else if (i < 453) s_wv[i-389]    = tanhf(vv);
        else if (i < 457) s_fg[i-453]    = sig_(vv);
        else if (i < 458) s_sc[1]        = sig_(vv);
        else if (i < 459) s_sc[2]        = sig_(vv);
        else              s_modes[i-459] = vv;
    }
    for (int i = tid; i < R_*N_; i += 256) s_rw[i] = rw[(size_t)b*R_*N_ + i];
    for (int i = tid; i < N_*W_; i += 256)
        s_mem[(i >> 6) * (W_+1) + (i & 63)] = mem[(size_t)b*N_*W_ + i];
    if (tid < N_) s_prec[tid] = prec[b*N_ + tid];
    __syncthreads();

    // 2. usage update, sort key, pre-update norms, head norms, modes softmax
    unsigned long long key = ~0ull;
    if (tid < N_) {
        float p = 1.0f;
        #pragma unroll
        for (int r = 0; r < R_; ++r) p *= 1.0f - s_fg[r] * s_rw[r*N_ + tid];
        float uo = usg[b*N_ + tid], w0 = ww[b*N_ + tid];
        float u = (uo + w0 - uo*w0) * p;
        s_usage[tid] = u;
        usg[b*N_ + tid] = u;
        unsigned int fb = __float_as_uint(u);
        fb = (fb & 0x80000000u) ? ~fb : (fb | 0x80000000u);
        key = ((unsigned long long)fb << 32) | (unsigned int)tid;
        float s = 0.0f;
        for (int w = 0; w < W_; ++w) { float m = s_mem[tid*(W_+1)+w]; s += m*m; }
        s_minv[tid] = 1.0f / (sqrtf(s) + EPSF);
    }
    if (tid >= 128 && tid < 128 + R_) {
        int r = tid - 128;
        float s = 0.0f;
        for (int w = 0; w < W_; ++w) { float kv = s_rkeys[r*W_+w]; s += kv*kv; }
        s_kinv[r] = 1.0f / (sqrtf(s) + EPSF);
    }
    if (tid == 132) {
        float s = 0.0f;
        for (int w = 0; w < W_; ++w) s += s_wkey[w]*s_wkey[w];
        s_sc[5] = 1.0f / (sqrtf(s) + EPSF);
    }
    if (tid >= 136 && tid < 136 + R_) {
        int r = tid - 136;
        float m0 = s_modes[r*3], m1 = s_modes[r*3+1], m2 = s_modes[r*3+2];
        float mx = fmaxf(m0, fmaxf(m1, m2));
        float e0 = expf(m0-mx), e1 = expf(m1-mx), e2 = expf(m2-mx);
        float inv = 1.0f / (e0 + e1 + e2);
        s_modes[r*3] = e0*inv; s_modes[r*3+1] = e1*inv; s_modes[r*3+2] = e2*inv;
    }
    __syncthreads();

    // 3. write-content dot (pre-update mem), then register bitonic sort
    if (tid < N_) {
        float d = 0.0f;
        for (int w = 0; w < W_; ++w) d += s_wkey[w] * s_mem[tid*(W_+1)+w];
        s_cw[tid] = d * s_minv[tid] * s_sc[5] * s_sc[0];
    }
    for (int k = 2; k <= N_; k <<= 1) {
        for (int j = k >> 1; j > 0; j >>= 1) {
            unsigned long long pk;
            if (j == 64) {
                if (tid < N_) s_key[tid] = key;
                __syncthreads();
                pk = (tid < N_) ? s_key[tid ^ 64] : key;
                __syncthreads();
            } else {
                pk = shflx64(key, j);
            }
            bool lower = (tid & j) == 0;
            bool asc   = (tid & k) == 0;
            if ((key > pk) == (lower == asc)) key = pk;
        }
    }

    // 4. allocation via shfl product-scan; wave2 does write softmax in parallel
    float su = 0.0f, ex = 1.0f; int sidx = 0;
    if (tid < N_) {
        sidx = (int)(key & 0xffffffffu);
        su = s_usage[sidx];
        float p = su;
        #pragma unroll
        for (int off = 1; off < 64; off <<= 1) {
            float pv = __shfl_up(p, off);
            if (lane >= off) p *= pv;
        }
        if (tid == 63) s_sc[7] = p;
        float e = __shfl_up(p, 1);
        ex = (lane == 0) ? 1.0f : e;
    }
    __syncthreads();
    if (tid < N_) {
        if (tid >= 64) ex *= s_sc[7];
        s_alloc[sidx] = (1.0f - su) * ex;
    }
    if (wid == 2) {
        float v0 = s_cw[lane], v1 = s_cw[lane+64];
        float m = fmaxf(v0, v1);
        #pragma unroll
        for (int o = 32; o >= 1; o >>= 1) m = fmaxf(m, __shfl_xor(m, o));
        float e0 = expf(v0 - m), e1 = expf(v1 - m);
        float s = e0 + e1;
        #pragma unroll
        for (int o = 32; o >= 1; o >>= 1) s += __shfl_xor(s, o);
        s_cw[lane] = e0; s_cw[lane+64] = e1;
        if (lane == 0) s_sc[4] = 1.0f / s;
    }
    __syncthreads();

    // 5. write weighting
    if (tid < N_) {
        float cwn = s_cw[tid] * s_sc[4];
        float w = s_sc[2] * (s_sc[1] * s_alloc[tid] + (1.0f - s_sc[1]) * cwn);
        s_ww[tid] = w;
        ww[b*N_ + tid] = w;
    }
    __syncthreads();

    // 6. memory update (all) + sum_ww (wave3)
    for (int i = tid; i < N_*W_; i += 256) {
        int n = i >> 6, w = i & 63;
        float m = s_mem[n*(W_+1)+w];
        m = m * (1.0f - s_ww[n]*s_ev[w]) + s_ww[n]*s_wv[w];
        s_mem[n*(W_+1)+w] = m;
        mem[(size_t)b*N_*W_ + i] = m;
    }
    if (wid == 3) {
        float s = s_ww[lane] + s_ww[lane+64];
        #pragma unroll
        for (int o = 32; o >= 1; o >>= 1) s += __shfl_xor(s, o);
        if (lane == 0) s_sc[6] = s;
    }
    __syncthreads();

    // 7. fused link update + fwd reduce + bwd partials (single pass over link)
    {
        int wv = wid, ln = lane;
        float bl0[R_], bl1[R_];
        #pragma unroll
        for (int r = 0; r < R_; ++r) { bl0[r] = 0.0f; bl1[r] = 0.0f; }
        size_t base = (size_t)b * N_ * N_;
        for (int row = wv*32; row < wv*32 + 32; ++row) {
            float wwr = s_ww[row];
            float l0 = link[base + row*N_ + ln];
            float l1 = link[base + row*N_ + 64 + ln];
            float n0 = (1.0f - wwr - s_ww[ln])      * l0 + wwr * s_prec[ln];
            float n1 = (1.0f - wwr - s_ww[64 + ln]) * l1 + wwr * s_prec[64 + ln];
            if (row == ln)      n0 = 0.0f;
            if (row == 64 + ln) n1 = 0.0f;
            link[base + row*N_ + ln]      = n0;
            link[base + row*N_ + 64 + ln] = n1;
            #pragma unroll
            for (int r = 0; r < R_; ++r) {
                float vv = n0 * s_rw[r*N_ + ln] + n1 * s_rw[r*N_ + 64 + ln];
                vv += __shfl_xor(vv, 32); vv += __shfl_xor(vv, 16); vv += __shfl_xor(vv, 8);
                vv += __shfl_xor(vv, 4);  vv += __shfl_xor(vv, 2);  vv += __shfl_xor(vv, 1);
                if (ln == 0) s_fwd[r*N_ + row] = vv;
                bl0[r] += n0 * s_rw[r*N_ + row];
                bl1[r] += n1 * s_rw[r*N_ + row];
            }
        }
        #pragma unroll
        for (int r = 0; r < R_; ++r) {
            s_bpart[wv][r][ln]      = bl0[r];
            s_bpart[wv][r][64 + ln] = bl1[r];
        }
    }
    __syncthreads();

    // 8. bwd combine + precedence + post-update norms
    if (tid < N_) {
        #pragma unroll
        for (int r = 0; r < R_; ++r)
            s_bwd[r*N_ + tid] = s_bpart[0][r][tid] + s_bpart[1][r][tid]
                              + s_bpart[2][r][tid] + s_bpart[3][r][tid];
        float p = (1.0f - s_sc[6]) * s_prec[tid] + s_ww[tid];
        prec[b*N_ + tid] = p;
        float s = 0.0f;
        for (int w = 0; w < W_; ++w) { float m = s_mem[tid*(W_+1)+w]; s += m*m; }
        s_minv[tid] = 1.0f / (sqrtf(s) + EPSF);
    }
    __syncthreads();

    // 9. read-content dots (post-update mem)
    for (int i = tid; i < R_*N_; i += 256) {
        int r = i >> 7, n = i & 127;
        float d = 0.0f;
        for (int w = 0; w < W_; ++w) d += s_rkeys[r*W_+w] * s_mem[n*(W_+1)+w];
        s_cr[i] = d * s_minv[n] * s_kinv[r] * s_rstr[r];
    }
    __syncthreads();

    // 10. per-head softmax (wave w = head w); fold 1/sum into mode coeff
    {
        int r = wid;
        float v0 = s_cr[r*N_ + lane], v1 = s_cr[r*N_ + lane + 64];
        float m = fmaxf(v0, v1);
        #pragma unroll
        for (int o = 32; o >= 1; o >>= 1) m = fmaxf(m, __shfl_xor(m, o));
        float e0 = expf(v0 - m), e1 = expf(v1 - m);
        float s = e0 + e1;
        #pragma unroll
        for (int o = 32; o >= 1; o >>= 1) s += __shfl_xor(s, o);
        s_cr[r*N_ + lane] = e0; s_cr[r*N_ + lane + 64] = e1;
        if (lane == 0) s_m1[r] = s_modes[r*3+1] / s;
    }
    __syncthreads();

    // 11. new read weights (reuse s_cr as combined)
    for (int i = tid; i < R_*N_; i += 256) {
        int r = i >> 7;
        float vv = s_modes[r*3] * s_bwd[i] + s_m1[r] * s_cr[i] + s_modes[r*3+2] * s_fwd[i];
        s_cr[i] = vv;
        rw[(size_t)b*R_*N_ + i] = vv;
    }
    __syncthreads();

    // 12. read vectors -> last_read ([k][b])
    for (int i = tid; i < R_*W_; i += 256) {
        int r = i >> 6, w = i & 63;
        float d = 0.0f;
        for (int n = 0; n < N_; ++n) d += s_cr[r*N_ + n] * s_mem[n*(W_+1)+w];
        lr[i*B_ + b] = d;
    }
}

extern "C" void kernel_launch(void* const* d_in, const int* in_sizes, int n_in,
                              void* d_out, int out_size, void* d_ws, size_t ws_size,
                              hipStream_t stream)
{
    const float* x    = (const float*)d_in[0];
    const float* Wih  = (const float*)d_in[1];
    const float* Whh  = (const float*)d_in[2];
    const float* bih  = (const float*)d_in[3];
    const float* bhh  = (const float*)d_in[4];
    const float* Wif  = (const float*)d_in[5];
    const float* bif  = (const float*)d_in[6];
    const float* Wemb = (const float*)d_in[7];
    const float* bemb = (const float*)d_in[8];
    float* out = (float*)d_out;
    float* ws  = (float*)d_ws;

    float* h0   = ws + OFF_H0;
    float* h1   = ws + OFF_H1;
    float* c    = ws + OFF_C;
    float* lr   = ws + OFF_LR;
    float* xi   = ws + OFF_XI;
    float* mem  = ws + OFF_MEM;
    float* link = ws + OFF_LINK;
    float* prec = ws + OFF_PREC;
    float* rwp  = ws + OFF_RW;
    float* wwp  = ws + OFF_WW;
    float* usg  = ws + OFF_USG;

    k_init<<<512, 256, 0, stream>>>(ws, WS_STATE);

    for (int t = 0; t < T_; ++t) {
        const float* hp = (t & 1) ? h1 : h0;
        float*       hn = (t & 1) ? h0 : h1;
        k_gates<<<144, 256, 0, stream>>>(x, Wih, Whh, bih, bhh, Wemb, bemb,
                                         hp, hn, c, lr, out, t);
        k_xi<<<30, 256, 0, stream>>>(Wif, bif, hn, xi);
        k_mem<<<32, 256, 0, stream>>>(xi, mem, link, prec, rwp, wwp, usg, lr);
    }
    k_out<<<16, 256, 0, stream>>>(Wemb, bemb, h0, lr, out);
}